// Round 3
// baseline (31.815 us; speedup 1.0000x reference)
//
#include <hip/hip_runtime.h>
#include <math.h>

#define BB 32
#define LL 512
#define DD 1024
#define TT 256
#define NK 136393      // total kept (s,e) pairs per batch
#define NK_LIN 131273  // offset(502) = 502*523/2
#define S_LIN 502
#define NEG_BIG  -3.0e38f   // finite stand-in for -inf in output
#define NEG_MASK -1.0e30f   // finite stand-in for masked logits

// ---------------- Kernel A: logits (+ fused flag scatter) ------------------
// One wave per row (4 rows/block); lane reads 4 float4s = 1 KB/instr/wave.
// Blocks 0..31 additionally scatter the ts/te flags for batch b=blockIdx.x.
__global__ __launch_bounds__(256) void logits_kernel(
    const float* __restrict__ text, const float* __restrict__ W,
    const float* __restrict__ bias, const int* __restrict__ mask,
    const int* __restrict__ tmap,
    float* __restrict__ slp, float* __restrict__ elp, float* __restrict__ mlp,
    int* __restrict__ fs, int* __restrict__ fe)
{
    __shared__ int tsl[LL];
    __shared__ int tel[LL];
    const int wid  = threadIdx.x >> 6;
    const int lane = threadIdx.x & 63;
    const int row  = blockIdx.x * 4 + wid;        // row = b*L + l
    const int b    = blockIdx.x;                  // only used if b < BB
    const int t    = threadIdx.x;

    if (b < BB) {                                 // block-uniform branch
        tsl[t] = 0; tsl[t + 256] = 0;
        tel[t] = 0; tel[t + 256] = 0;
        __syncthreads();
        int s0 = tmap[((size_t)b * TT + t) * 2 + 0];
        int e0 = tmap[((size_t)b * TT + t) * 2 + 1] - 1;
        s0 = min(max(s0, 0), LL - 1);
        e0 = min(max(e0, 0), LL - 1);
        tsl[s0] = 1;                              // benign race: all write 1
        tel[e0] = 1;
        __syncthreads();
    }

    // ---- GEMV: 3 dot products of length 1024 ----
    const float4* t4 = (const float4*)(text + (size_t)row * DD);
    float a0 = 0.f, a1 = 0.f, a2 = 0.f;
#pragma unroll
    for (int j = 0; j < 4; ++j) {
        const int fi = lane + j * 64;
        float4 v = t4[fi];
        const float* wp = W + (size_t)fi * 12;
        a0 += v.x * wp[0];  a1 += v.x * wp[1];  a2 += v.x * wp[2];
        a0 += v.y * wp[3];  a1 += v.y * wp[4];  a2 += v.y * wp[5];
        a0 += v.z * wp[6];  a1 += v.z * wp[7];  a2 += v.z * wp[8];
        a0 += v.w * wp[9];  a1 += v.w * wp[10]; a2 += v.w * wp[11];
    }
#pragma unroll
    for (int off = 32; off; off >>= 1) {
        a0 += __shfl_down(a0, off);
        a1 += __shfl_down(a1, off);
        a2 += __shfl_down(a2, off);
    }
    if (lane == 0) {
        const int m = mask[row];
        slp[row] = (m == 1) ? a0 + bias[0] : NEG_MASK;
        elp[row] = (m == 1) ? a1 + bias[1] : NEG_MASK;
        mlp[row] = (m == 1) ? a2 + bias[2] : NEG_MASK;
    }

    if (b < BB) {
        const int i0 = b * LL + t, i1 = i0 + 256;
        fs[i0] = (t != 0 && mask[i0] == 1 && tsl[t]) ? 1 : 0;
        fs[i1] = (mask[i1] == 1 && tsl[t + 256]) ? 1 : 0;
        fe[i0] = (t != 0 && tel[t]) ? 1 : 0;
        fe[i1] = tel[t + 256] ? 1 : 0;
    }
}

// ---------------- Kernel C: emit kept pairs (scores + bounds) --------------
// offset(s) = s*(s+21)/2 for s<=502 ; linear (stride 512) after.
// Valid pairs have 0 <= e-s <= 10 -> cumsum difference == window sum (<=11).
__global__ __launch_bounds__(256) void out_kernel(
    const float* __restrict__ slp, const float* __restrict__ elp,
    const float* __restrict__ mlp,
    const int* __restrict__ fs, const int* __restrict__ fe,
    float* __restrict__ out)
{
    const int k = blockIdx.x * 256 + threadIdx.x;
    const int b = blockIdx.y;
    if (k >= NK) return;

    int s, e;
    if (k >= NK_LIN) {
        const int r = k - NK_LIN;
        s = S_LIN + (r >> 9);
        e = r & 511;
    } else {
        float f = sqrtf(8.0f * (float)k + 441.0f);
        s = (int)((f - 21.0f) * 0.5f);
        if (s < 0) s = 0;
        if (s > 501) s = 501;
        while ((s + 1) * (s + 22) / 2 <= k) ++s;   // offset(s+1) <= k
        while (s * (s + 21) / 2 > k) --s;          // offset(s)   >  k
        e = k - s * (s + 21) / 2;
    }

    const int base = b * LL;
    float score = NEG_BIG;
    if (s <= e && fs[base + s] && fe[base + e]) {
        float w = 0.f;
        for (int l = s; l <= e; ++l) w += mlp[base + l];   // <= 11 terms, L1-hot
        score = (slp[base + s] + elp[base + e]) + w;
    }

    out[(size_t)b * NK + k] = score;

    float2* bptr = (float2*)(out + (size_t)BB * NK);
    bptr[(size_t)b * NK + k] = make_float2((float)s, (float)e);
}

extern "C" void kernel_launch(void* const* d_in, const int* in_sizes, int n_in,
                              void* d_out, int out_size, void* d_ws, size_t ws_size,
                              hipStream_t stream) {
    const float* text = (const float*)d_in[0];   // (B,L,D) f32
    const int*   mask = (const int*)d_in[1];     // (B,L) i32
    const int*   tmap = (const int*)d_in[2];     // (B,T,2) i32
    const float* W    = (const float*)d_in[3];   // (D,3) f32
    const float* bias = (const float*)d_in[4];   // (3,) f32
    float* out = (float*)d_out;

    float* slp = (float*)d_ws;                   // B*L each
    float* elp = slp + (size_t)BB * LL;
    float* mlp = elp + (size_t)BB * LL;
    int*   fs  = (int*)(mlp + (size_t)BB * LL);
    int*   fe  = fs + (size_t)BB * LL;

    logits_kernel<<<BB * LL / 4, 256, 0, stream>>>(text, W, bias, mask, tmap,
                                                   slp, elp, mlp, fs, fe);
    dim3 g3((NK + 255) / 256, BB);
    out_kernel<<<g3, 256, 0, stream>>>(slp, elp, mlp, fs, fe, out);
}